// Round 9
// baseline (348.746 us; speedup 1.0000x reference)
//
#include <hip/hip_runtime.h>
#include <cstdint>
#include <cstddef>

typedef unsigned short u16;
typedef unsigned int   u32;
typedef __bf16 bf16x8 __attribute__((ext_vector_type(8)));
typedef float  f32x4  __attribute__((ext_vector_type(4)));

#define BS   8192
#define DIMM 512
#define NH   8
#define HD   64
#define SEQ  2048
#define DFF  2048
#define NQKV 1536

// async global->LDS, 16B/lane; LDS dest = wave-uniform base + lane*16
#define GLD16(g, l) __builtin_amdgcn_global_load_lds( \
    (__attribute__((address_space(1))) const void*)(g), \
    (__attribute__((address_space(3))) void*)(l), 16, 0, 0)

#define SBAR   __builtin_amdgcn_s_barrier()
#define VMCNT4 asm volatile("s_waitcnt vmcnt(4)" ::: "memory")
#define VMCNT0 asm volatile("s_waitcnt vmcnt(0)" ::: "memory")
#define LGKM0  asm volatile("s_waitcnt lgkmcnt(0)" ::: "memory")

__device__ __forceinline__ float b2f(u16 s) {
  u32 u = ((u32)s) << 16;
  float f; __builtin_memcpy(&f, &u, 4); return f;
}
__device__ __forceinline__ u16 f2b(float f) {
  u32 u; __builtin_memcpy(&u, &f, 4);
  u += 0x7fffu + ((u >> 16) & 1u);   // RNE
  return (u16)(u >> 16);
}
__device__ __forceinline__ u16 f2b_rtz(float f) {
  u32 u; __builtin_memcpy(&u, &f, 4);
  return (u16)(u >> 16);            // truncate; bias cancels in softmax norm
}

// ---- merged weight transpose+convert: 4 weights, one launch ---------------
#define SZ_QKV (DIMM * NQKV)
#define SZ_PRJ (DIMM * DIMM)
#define SZ_F1  (DIMM * DFF)
#define SZ_F2  (DFF * DIMM)
__global__ __launch_bounds__(256) void transpose_all_k(
    const float* __restrict__ w_qkv, const float* __restrict__ w_prj,
    const float* __restrict__ w_f1,  const float* __restrict__ w_f2,
    u16* __restrict__ o_qkv, u16* __restrict__ o_prj,
    u16* __restrict__ o_f1,  u16* __restrict__ o_f2) {
  int idx = blockIdx.x * 256 + threadIdx.x;
  const float* W; u16* O; int Kd, Nd, off;
  if (idx < SZ_QKV)                         { W = w_qkv; O = o_qkv; Kd = DIMM; Nd = NQKV; off = idx; }
  else if (idx < SZ_QKV + SZ_PRJ)           { W = w_prj; O = o_prj; Kd = DIMM; Nd = DIMM; off = idx - SZ_QKV; }
  else if (idx < SZ_QKV + SZ_PRJ + SZ_F1)   { W = w_f1;  O = o_f1;  Kd = DIMM; Nd = DFF;  off = idx - SZ_QKV - SZ_PRJ; }
  else                                      { W = w_f2;  O = o_f2;  Kd = DFF;  Nd = DIMM; off = idx - SZ_QKV - SZ_PRJ - SZ_F1; }
  int n = off / Kd, k = off - n * Kd;
  O[off] = f2b(W[(size_t)k * Nd + n]);
}

// ---------------- LayerNorm f32 -> bf16 (one wave per 512-row) -------------
__global__ __launch_bounds__(256) void ln_f32b_k(const float* __restrict__ X,
    const float* __restrict__ G, const float* __restrict__ Bb, u16* __restrict__ out) {
  int w = threadIdx.x >> 6, lane = threadIdx.x & 63;
  size_t row = (size_t)blockIdx.x * 4 + w;
  const float* xr = X + row * DIMM;
  float v[8];
  *(float4*)&v[0] = *(const float4*)(xr + lane * 8);
  *(float4*)&v[4] = *(const float4*)(xr + lane * 8 + 4);
  float s = 0.f, s2 = 0.f;
#pragma unroll
  for (int j = 0; j < 8; j++) { s += v[j]; s2 += v[j] * v[j]; }
#pragma unroll
  for (int m = 1; m < 64; m <<= 1) { s += __shfl_xor(s, m); s2 += __shfl_xor(s2, m); }
  float mu = s * (1.f / DIMM);
  float rsd = rsqrtf(s2 * (1.f / DIMM) - mu * mu + 1e-5f);
  float g[8], bb[8];
  *(float4*)&g[0]  = *(const float4*)(G + lane * 8);
  *(float4*)&g[4]  = *(const float4*)(G + lane * 8 + 4);
  *(float4*)&bb[0] = *(const float4*)(Bb + lane * 8);
  *(float4*)&bb[4] = *(const float4*)(Bb + lane * 8 + 4);
  uint4 ov; u16* os = (u16*)&ov;
#pragma unroll
  for (int j = 0; j < 8; j++) os[j] = f2b((v[j] - mu) * rsd * g[j] + bb[j]);
  *(uint4*)(out + row * DIMM + lane * 8) = ov;
}

// -------- MFMA GEMM: C[M,N] = A[M,K](bf16) @ BT[N,K](bf16)^T + bias --------
// Counted-vmcnt pipeline (T3+T4): raw s_barrier, NEVER vmcnt(0) in steady
// state. Per k-step: frag ds_reads -> lgkmcnt(0) -> barrier (read-before-
// overwrite) -> STAGE(ts+2) -> MFMA -> vmcnt(4) -> barrier.
// LDS tiles XOR-swizzled (T2) via pre-swizzled GLOBAL source; read side
// applies the same involution. Macros (not lambdas): R2/R3 toolchain fail.
// EPI 0: f32   EPI 1: f32 (v + f32 resid)   EPI 2: gelu->bf16   EPI 3: bf16
template <int EPI, int TM, int TN, int BK>
__global__ __launch_bounds__(256) void gemm_bt(const u16* __restrict__ A,
    const u16* __restrict__ BT, const float* __restrict__ bias,
    void* __restrict__ Cout, const float* __restrict__ resid, int N, int Kd) {
  constexpr int CPR  = BK / 8;               // 16B chunks per row
  constexpr int CPRB = (BK == 64) ? 3 : 2;
  constexpr int RS   = (BK == 64) ? 0 : 1;   // swizzle: vary per 128B window
  constexpr int KK   = BK / 32;
  constexpr int WROWS = (TN == 128) ? TM / 2 : TM / 4;
  constexpr int MT   = WROWS / 16;
  constexpr int ALOOP = TM * CPR / 256;      // == 2 for all configs used
  constexpr int BLOOP = TN * CPR / 256;      // == 2 for all configs used
  __shared__ __align__(16) u16 a_s[2][TM * BK];
  __shared__ __align__(16) u16 b_s[2][TN * BK];
  int t = threadIdx.x, lane = t & 63, w = t >> 6;
  int l15 = lane & 15, quad = lane >> 4;
  int gx = gridDim.x;
  int lid = blockIdx.x + gx * blockIdx.y;
  int per = (gx * gridDim.y) >> 3;
  int nid = (lid & 7) * per + (lid >> 3);    // XCD-contiguous remap
  int bx = nid % gx, by = nid / gx;
  int m0 = by * TM, n0 = bx * TN;
  int wm = (TN == 128) ? (w >> 1) * WROWS : w * WROWS;
  int wn = (TN == 128) ? (w & 1) * 64 : 0;
  f32x4 z4 = {0.f, 0.f, 0.f, 0.f};
  f32x4 acc[MT][4];
#pragma unroll
  for (int i = 0; i < MT; i++)
#pragma unroll
    for (int j = 0; j < 4; j++) acc[i][j] = z4;

#define GSTAGE(buf, ts) do {                                                  \
    int k0_ = (ts) * BK;                                                      \
    _Pragma("unroll")                                                         \
    for (int i = 0; i < ALOOP; i++) {                                         \
      int c_ = t + i * 256;                                                   \
      int row_ = c_ >> CPRB, pos_ = c_ & (CPR - 1);                           \
      int ch_ = (pos_ ^ (row_ >> RS)) & (CPR - 1);                            \
      GLD16(A + (size_t)(m0 + row_) * Kd + k0_ + ch_ * 8, &a_s[buf][c_ * 8]); \
    }                                                                         \
    _Pragma("unroll")                                                         \
    for (int i = 0; i < BLOOP; i++) {                                         \
      int c_ = t + i * 256;                                                   \
      int row_ = c_ >> CPRB, pos_ = c_ & (CPR - 1);                           \
      int ch_ = (pos_ ^ (row_ >> RS)) & (CPR - 1);                            \
      GLD16(BT + (size_t)(n0 + row_) * Kd + k0_ + ch_ * 8, &b_s[buf][c_ * 8]);\
    }                                                                         \
  } while (0)

#define GFRAG(buf) do {                                                       \
    _Pragma("unroll")                                                         \
    for (int mt = 0; mt < MT; mt++) {                                         \
      _Pragma("unroll")                                                       \
      for (int kk = 0; kk < KK; kk++) {                                       \
        int row_ = wm + mt * 16 + l15;                                        \
        int pos_ = ((kk * 4 + quad) ^ (row_ >> RS)) & (CPR - 1);              \
        af[mt][kk] = *(const bf16x8*)&a_s[buf][row_ * BK + pos_ * 8];         \
      }                                                                       \
    }                                                                         \
    _Pragma("unroll")                                                         \
    for (int nt = 0; nt < 4; nt++) {                                          \
      _Pragma("unroll")                                                       \
      for (int kk = 0; kk < KK; kk++) {                                       \
        int row_ = wn + nt * 16 + l15;                                        \
        int pos_ = ((kk * 4 + quad) ^ (row_ >> RS)) & (CPR - 1);              \
        bfm[nt][kk] = *(const bf16x8*)&b_s[buf][row_ * BK + pos_ * 8];        \
      }                                                                       \
    }                                                                         \
  } while (0)

#define GMFMA() do {                                                          \
    _Pragma("unroll")                                                         \
    for (int kk = 0; kk < KK; kk++)                                           \
      _Pragma("unroll")                                                       \
      for (int mt = 0; mt < MT; mt++)                                         \
        _Pragma("unroll")                                                     \
        for (int nt = 0; nt < 4; nt++)                                        \
          acc[mt][nt] = __builtin_amdgcn_mfma_f32_16x16x32_bf16(              \
              af[mt][kk], bfm[nt][kk], acc[mt][nt], 0, 0, 0);                 \
  } while (0)

  bf16x8 af[MT][KK], bfm[4][KK];
  GSTAGE(0, 0);
  GSTAGE(1, 1);
  VMCNT4;                          // tile 0 landed; tile 1's 4 still in flight
  SBAR;
  int nsteps = Kd / BK;            // always even (8/16/32)
  for (int ts = 0; ts < nsteps; ts += 2) {
    GFRAG(0);
    LGKM0;
    SBAR;                          // all waves done reading buf0 -> overwrite ok
    if (ts + 2 < nsteps) {
      GSTAGE(0, ts + 2);
      GMFMA();
      VMCNT4;                      // tile ts+1 landed (ts+2's 4 remain)
    } else {
      GMFMA();
      VMCNT0;
    }
    SBAR;
    GFRAG(1);
    LGKM0;
    SBAR;
    if (ts + 3 < nsteps) {
      GSTAGE(1, ts + 3);
      GMFMA();
      VMCNT4;
    } else {
      GMFMA();
      VMCNT0;
    }
    SBAR;
  }
#undef GSTAGE
#undef GFRAG
#undef GMFMA

#pragma unroll
  for (int nt = 0; nt < 4; nt++) {
    int col = n0 + wn + nt * 16 + l15;
    float bv = bias[col];
#pragma unroll
    for (int mt = 0; mt < MT; mt++) {
#pragma unroll
      for (int r = 0; r < 4; r++) {
        int rw = m0 + wm + mt * 16 + quad * 4 + r;
        float v = acc[mt][nt][r] + bv;
        size_t off = (size_t)rw * N + col;
        if (EPI == 0) {
          ((float*)Cout)[off] = v;
        } else if (EPI == 1) {
          ((float*)Cout)[off] = v + resid[off];
        } else if (EPI == 2) {
          ((u16*)Cout)[off] = f2b(0.5f * v * (1.f + erff(v * 0.70710678118654752f)));
        } else {
          ((u16*)Cout)[off] = f2b(v);
        }
      }
    }
  }
}

// ------- RoPE + reorg qkv[BS][1536] bf16 -> Q,K,V [B*H][S][HD] bf16 --------
// Q pre-scaled by (1/sqrt(HD)) * log2(e) so attention can use exp2.
#define QSCALE 0.18033688f
__global__ __launch_bounds__(256) void rope_k(const u16* __restrict__ qkv,
    const float* __restrict__ C, const float* __restrict__ Sn,
    u16* __restrict__ Qo, u16* __restrict__ Ko, u16* __restrict__ Vo) {
  int idx = blockIdx.x * 256 + threadIdx.x;   // one 8-elem chunk
  int row = idx / 192;                        // (b*SEQ + s)
  int cn = idx - row * 192;
  int n0 = cn * 8;
  int comp = n0 >> 9;
  int hh = (n0 >> 6) & 7;
  int d0 = n0 & 63;
  int b = row >> 11, s = row & 2047;
  const u16* src = qkv + (size_t)row * NQKV;
  uint4 val = *(const uint4*)(src + n0);
  u16* vs = (u16*)&val;
  size_t oo = ((size_t)((b << 3) + hh) * SEQ + s) * HD + d0;
  if (comp == 2) { *(uint4*)(Vo + oo) = val; return; }
  uint4 pv = *(const uint4*)(src + (n0 ^ 32));        // rotate-half partner
  u16* ps = (u16*)&pv;
  float cv[8], sv[8];
  *(float4*)&cv[0] = *(const float4*)(C + s * HD + d0);
  *(float4*)&cv[4] = *(const float4*)(C + s * HD + d0 + 4);
  *(float4*)&sv[0] = *(const float4*)(Sn + s * HD + d0);
  *(float4*)&sv[4] = *(const float4*)(Sn + s * HD + d0 + 4);
  float sgn = (d0 & 32) ? 1.f : -1.f;
  float sc = (comp == 0) ? QSCALE : 1.f;
  uint4 ov; u16* os = (u16*)&ov;
#pragma unroll
  for (int j = 0; j < 8; j++)
    os[j] = f2b(sc * (b2f(vs[j]) * cv[j] + sgn * b2f(ps[j]) * sv[j]));
  *(uint4*)((comp == 0 ? Qo : Ko) + oo) = ov;
}

// ------------- V transpose: [bh][s][d] -> Vt [bh][d][s] (bf16) -------------
__global__ __launch_bounds__(256) void vtrans_k(const u16* __restrict__ V,
                                                u16* __restrict__ Vt) {
  __shared__ u16 ld[64 * 72];
  int t = threadIdx.x;
  int bh = blockIdx.x >> 5;          // 32 s-tiles per bh
  int s0 = (blockIdx.x & 31) * 64;
  const u16* src = V + (size_t)bh * SEQ * HD + (size_t)s0 * HD;
  u16* dst = Vt + (size_t)bh * SEQ * HD;
#pragma unroll
  for (int i = 0; i < 2; i++) {
    int c = t + i * 256, s = c >> 3, cp = c & 7;
    *(uint4*)&ld[s * 72 + ((cp ^ (s >> 3)) << 3)] =
        *(const uint4*)(src + (size_t)s * HD + cp * 8);
  }
  __syncthreads();
#pragma unroll
  for (int i = 0; i < 2; i++) {
    int c = t + i * 256, d = c >> 3, sc = c & 7;
    uint4 ov; u16* os = (u16*)&ov;
#pragma unroll
    for (int j = 0; j < 8; j++) {
      int s = sc * 8 + j;
      os[j] = ld[s * 72 + (((d >> 3) ^ (s >> 3)) << 3) + (d & 7)];
    }
    *(uint4*)(dst + (size_t)d * SEQ + s0 + sc * 8) = ov;
  }
}

// ------------- flash attention, K-SPLIT, 256-row q-tile ---------------------
// R7 showed attn is LDS-BANDWIDTH-bound (dur invariant under 2x occupancy;
// per-CU LDS bytes/85 B/cyc ~= measured dur). Fix: amortize the dominant
// K/V fragment reads over 2x output -- q-tile 256, each of 8 waves owns 32
// q-rows (2 row-sets). kb/vb read ONCE per wave per tile, feed both row-sets.
// LDS bytes/tile/block: 208KB per 256 q-rows vs 2x160KB before (1.54x less).
// K-split x2 retained (sum-softmax partials add exactly; combine divides).
// 512 blocks, LDS 55.3KB -> 2 blocks/CU.
__global__ __launch_bounds__(512) void attn_flash_k(const u16* __restrict__ Qg,
    const u16* __restrict__ Kg, const u16* __restrict__ Vtg,
    float* __restrict__ Op, float* __restrict__ Lp) {
  __shared__ u16 q_s[256 * 72];    // Q tile, then P (rows = q rows)
  __shared__ u16 k_s[64 * 72];     // K rows (key-major)
  __shared__ u16 vt_s[64 * 72];    // V^T rows (d-major)
  int t = threadIdx.x, lane = t & 63, w = t >> 6;   // w in 0..7
  int l15 = lane & 15, quad = lane >> 4;
  int lid = blockIdx.x;                      // 512 blocks
  int nid = (lid & 7) * 64 + (lid >> 3);     // XCD-contiguous remap
  int bhh = nid >> 3;                        // 64 (bh,half) groups
  int bh = bhh >> 1, half = bhh & 1;
  int qt0 = (nid & 7) * 256;
  int kt0 = half << 10;                      // 0 or 1024
  int b = bh >> 3, h = bh & 7;
  const u16* Qp = Qg + (size_t)bh * SEQ * HD;
  const u16* Kp = Kg + (size_t)bh * SEQ * HD;
  const u16* Vp = Vtg + (size_t)bh * SEQ * HD;   // [d][s]
  int row = t >> 3, ch = t & 7;    // staging: K -> row=key, V^T -> row=d

  // P-swizzle constants. Wave rows: w*32 + rs*16 + (quad*4+r | l15).
  // write row>>2 & 7 = rs*4+quad ; read row>>2 & 7 = rs*4+(l15>>2).
  int pcol[2][4], pch[2][2];
#pragma unroll
  for (int rs = 0; rs < 2; rs++) {
    int sW = (rs * 4 + quad) & 7;
    int sR = (rs * 4 + (l15 >> 2)) & 7;
#pragma unroll
    for (int n = 0; n < 4; n++)
      pcol[rs][n] = (((n * 2 + (l15 >> 3)) ^ sW) << 3) + (l15 & 7);
#pragma unroll
    for (int kk = 0; kk < 2; kk++)
      pch[rs][kk] = ((kk * 4 + quad) ^ sR) << 3;
  }

  // stage Q tile (256 rows)
#pragma unroll
  for (int i = 0; i < 4; i++) {
    int c = t + i * 512, qr = c >> 3, qc = c & 7;
    *(uint4*)&q_s[qr * 72 + qc * 8] = *(const uint4*)(Qp + (size_t)(qt0 + qr) * HD + qc * 8);
  }
  // prefetch K/V tile 0 of this half into registers
  uint4 kr = *(const uint4*)(Kp + (size_t)(kt0 + row) * HD + ch * 8);
  uint4 vr = *(const uint4*)(Vp + (size_t)row * SEQ + kt0 + ch * 8);
  __syncthreads();
  bf16x8 qa[2][2];
#pragma unroll
  for (int rs = 0; rs < 2; rs++) {
    qa[rs][0] = *(const bf16x8*)&q_s[(w * 32 + rs * 16 + l15) * 72 + quad * 8];
    qa[rs][1] = *(const bf16x8*)&q_s[(w * 32 + rs * 16 + l15) * 72 + 32 + quad * 8];
  }
  u16* p_s = q_s;                  // q_s dead after qa load
  f32x4 z4 = {0.f, 0.f, 0.f, 0.f};
  f32x4 of[2][4];
#pragma unroll
  for (int rs = 0; rs < 2; rs++)
#pragma unroll
    for (int n = 0; n < 4; n++) of[rs][n] = z4;
  float lrun[2][4] = {};

  for (int kt = kt0; kt < kt0 + 1024; kt += 64) {
    __syncthreads();               // prior tile's LDS reads drained
    *(uint4*)&k_s[row * 72 + ch * 8] = kr;
    *(uint4*)&vt_s[row * 72 + ch * 8] = vr;
    __syncthreads();               // staging visible
    if (kt + 64 < kt0 + 1024) {    // prefetch next tile
      kr = *(const uint4*)(Kp + (size_t)(kt + 64 + row) * HD + ch * 8);
      vr = *(const uint4*)(Vp + (size_t)row * SEQ + kt + 64 + ch * 8);
    }
    // S = Q K^T: sf[rs][n] = S[q=w*32+rs*16+quad*4+r][key=n*16+l15]
    // kb read ONCE per (kk,n), feeds both row-sets (the LDS-BW lever).
    f32x4 sf[2][4];
#pragma unroll
    for (int rs = 0; rs < 2; rs++)
#pragma unroll
      for (int n = 0; n < 4; n++) sf[rs][n] = z4;
    __builtin_amdgcn_s_setprio(1);
#pragma unroll
    for (int kk = 0; kk < 2; kk++)
#pragma unroll
      for (int n = 0; n < 4; n++) {
        bf16x8 kb = *(const bf16x8*)&k_s[(n * 16 + l15) * 72 + kk * 32 + quad * 8];
        sf[0][n] = __builtin_amdgcn_mfma_f32_16x16x32_bf16(qa[0][kk], kb, sf[0][n], 0, 0, 0);
        sf[1][n] = __builtin_amdgcn_mfma_f32_16x16x32_bf16(qa[1][kk], kb, sf[1][n], 0, 0, 0);
      }
    __builtin_amdgcn_s_setprio(0);
    // p = exp2(s) (Q carried log2e/8); store RTZ bf16 swizzled; defer norm
#pragma unroll
    for (int rs = 0; rs < 2; rs++)
#pragma unroll
      for (int r = 0; r < 4; r++) {
        int prow = (w * 32 + rs * 16 + quad * 4 + r) * 72;
#pragma unroll
        for (int n = 0; n < 4; n++) {
          float pp = exp2f(sf[rs][n][r]);
          lrun[rs][r] += pp;
          p_s[prow + pcol[rs][n]] = f2b_rtz(pp);
        }
      }
    // O += P V: vb read ONCE per (kk,n), feeds both row-sets
    __builtin_amdgcn_s_setprio(1);
#pragma unroll
    for (int kk = 0; kk < 2; kk++) {
      bf16x8 pa0 = *(const bf16x8*)&p_s[(w * 32 + l15) * 72 + pch[0][kk]];
      bf16x8 pa1 = *(const bf16x8*)&p_s[(w * 32 + 16 + l15) * 72 + pch[1][kk]];
#pragma unroll
      for (int n = 0; n < 4; n++) {
        bf16x8 vb = *(const bf16x8*)&vt_s[(n * 16 + l15) * 72 + kk * 32 + quad * 8];
        of[0][n] = __builtin_amdgcn_mfma_f32_16x16x32_bf16(pa0, vb, of[0][n], 0, 0, 0);
        of[1][n] = __builtin_amdgcn_mfma_f32_16x16x32_bf16(pa1, vb, of[1][n], 0, 0, 0);
      }
    }
    __builtin_amdgcn_s_setprio(0);
  }
  // write unnormalized partials
  float* Opb = Op + (size_t)half * ((size_t)BS * DIMM);
  float* Lpb = Lp + (size_t)half * (32 * 2048);
#pragma unroll
  for (int rs = 0; rs < 2; rs++)
#pragma unroll
    for (int r = 0; r < 4; r++) {
      float l = lrun[rs][r];
#pragma unroll
      for (int m = 1; m < 16; m <<= 1) l += __shfl_xor(l, m);
      int s = qt0 + w * 32 + rs * 16 + quad * 4 + r;
      size_t orow = (size_t)b * SEQ + s;
#pragma unroll
      for (int n = 0; n < 4; n++)
        Opb[orow * DIMM + h * HD + n * 16 + l15] = of[rs][n][r];
      if (l15 == 0) Lpb[(bh << 11) + s] = l;
    }
}

// --------- combine: ob = (O0+O1)/(l0+l1) -> bf16, memory-bound -------------
__global__ __launch_bounds__(256) void attn_combine_k(const float* __restrict__ Op,
    const float* __restrict__ Lp, u16* __restrict__ ob) {
  int idx = blockIdx.x * 256 + threadIdx.x;
  size_t off8 = (size_t)idx * 8;
  int row = (int)(off8 >> 9), col = (int)(off8 & 511);
  int h = col >> 6;
  int b = row >> 11, s = row & 2047;
  int li = (((b << 3) + h) << 11) + s;
  float inv = 1.f / (Lp[li] + Lp[li + (32 << 11)]);
  const float* O0 = Op + off8;
  const float* O1 = Op + (size_t)BS * DIMM + off8;
  float4 a0 = *(const float4*)(O0);
  float4 a1 = *(const float4*)(O0 + 4);
  float4 c0 = *(const float4*)(O1);
  float4 c1 = *(const float4*)(O1 + 4);
  uint4 ov; u16* os = (u16*)&ov;
  os[0] = f2b((a0.x + c0.x) * inv); os[1] = f2b((a0.y + c0.y) * inv);
  os[2] = f2b((a0.z + c0.z) * inv); os[3] = f2b((a0.w + c0.w) * inv);
  os[4] = f2b((a1.x + c1.x) * inv); os[5] = f2b((a1.y + c1.y) * inv);
  os[6] = f2b((a1.z + c1.z) * inv); os[7] = f2b((a1.w + c1.w) * inv);
  *(uint4*)(ob + off8) = ov;
}

// ---------------------------------------------------------------------------
extern "C" void kernel_launch(void* const* d_in, const int* in_sizes, int n_in,
                              void* d_out, int out_size, void* d_ws, size_t ws_size,
                              hipStream_t stream) {
  const float* x    = (const float*)d_in[0];
  const float* rc   = (const float*)d_in[1];
  const float* rsn  = (const float*)d_in[2];
  const float* n1g  = (const float*)d_in[3];
  const float* n1b  = (const float*)d_in[4];
  const float* n2g  = (const float*)d_in[5];
  const float* n2b  = (const float*)d_in[6];
  const float* wqkv = (const float*)d_in[7];
  const float* bqkv = (const float*)d_in[8];
  const float* wprj = (const float*)d_in[9];
  const float* bprj = (const float*)d_in[10];
  const float* wf1  = (const float*)d_in[11];
  const float* bf1  = (const float*)d_in[12];
  const float* wf2  = (const float*)d_in[13];
  const float* bf2  = (const float*)d_in[14];

  char* p = (char*)d_ws;
  u16*   wqkvT = (u16*)p;                   // 1.5 MB
  u16*   wprjT = (u16*)(p + (2u  << 20));   // 0.5 MB
  u16*   wf1T  = (u16*)(p + (3u  << 20));   // 2 MB
  u16*   wf2T  = (u16*)(p + (5u  << 20));   // 2 MB
  u16*   h1    = (u16*)(p + (8u  << 20));   // 8 MB bf16: LN1 out / ob / h2
  u16*   qkvb  = (u16*)(p + (16u << 20));   // 24 MB bf16 (dead after rope)
  float* Opart = (float*)(p + (16u << 20)); // 32 MB f32 partials (16-48)
  u16*   Vt    = (u16*)(p + (48u << 20));   // 8 MB bf16 (48-56)
  float* Lpart = (float*)(p + (56u << 20)); // 0.5 MB (56-56.5)
  u16*   Qb    = (u16*)(p + (64u << 20));   // 8 MB bf16
  u16*   Kb    = (u16*)(p + (72u << 20));   // 8 MB bf16
  u16*   Vb    = (u16*)(p + (80u << 20));   // 8 MB bf16
  float* x2    = (float*)(p + (88u << 20)); // 16 MB f32 residual stream
  u16*   ob    = h1;                        // h1 dead after QKV gemm
  u16*   h2    = h1;                        // ob dead after proj gemm
  u16*   mid   = qkvb;                      // 32 MB bf16 region (Opart dead)

  transpose_all_k<<<dim3((SZ_QKV + SZ_PRJ + SZ_F1 + SZ_F2) / 256), 256, 0, stream>>>(
      wqkv, wprj, wf1, wf2, wqkvT, wprjT, wf1T, wf2T);

  ln_f32b_k<<<dim3(BS / 4), 256, 0, stream>>>(x, n1g, n1b, h1);

  gemm_bt<3, 128, 128, 32><<<dim3(NQKV / 128, BS / 128), 256, 0, stream>>>(h1, wqkvT, bqkv, qkvb, nullptr, NQKV, DIMM);

  rope_k<<<dim3(BS * NQKV / 8 / 256), 256, 0, stream>>>(qkvb, rc, rsn, Qb, Kb, Vb);

  vtrans_k<<<dim3(32 * (SEQ / 64)), 256, 0, stream>>>(Vb, Vt);

  attn_flash_k<<<dim3(2 * 32 * (SEQ / 256)), 512, 0, stream>>>(Qb, Kb, Vt, Opart, Lpart);

  attn_combine_k<<<dim3(BS * DIMM / 8 / 256), 256, 0, stream>>>(Opart, Lpart, ob);

  gemm_bt<1, 64, 64, 64><<<dim3(DIMM / 64, BS / 64), 256, 0, stream>>>(ob, wprjT, bprj, x2, x, DIMM, DIMM);

  ln_f32b_k<<<dim3(BS / 4), 256, 0, stream>>>(x2, n2g, n2b, h2);

  gemm_bt<2, 128, 128, 32><<<dim3(DFF / 128, BS / 128), 256, 0, stream>>>(h2, wf1T, bf1, mid, nullptr, DFF, DIMM);

  gemm_bt<1, 64, 64, 64><<<dim3(DIMM / 64, BS / 64), 256, 0, stream>>>(mid, wf2T, bf2, (float*)d_out, x2, DIMM, DFF);
}

// Round 10
// 299.255 us; speedup vs baseline: 1.1654x; 1.1654x over previous
//
#include <hip/hip_runtime.h>
#include <cstdint>
#include <cstddef>

typedef unsigned short u16;
typedef unsigned int   u32;
typedef __bf16 bf16x8 __attribute__((ext_vector_type(8)));
typedef float  f32x4  __attribute__((ext_vector_type(4)));

#define BS   8192
#define DIMM 512
#define NH   8
#define HD   64
#define SEQ  2048
#define DFF  2048
#define NQKV 1536

// async global->LDS, 16B/lane; LDS dest = wave-uniform base + lane*16
#define GLD16(g, l) __builtin_amdgcn_global_load_lds( \
    (__attribute__((address_space(1))) const void*)(g), \
    (__attribute__((address_space(3))) void*)(l), 16, 0, 0)

__device__ __forceinline__ float b2f(u16 s) {
  u32 u = ((u32)s) << 16;
  float f; __builtin_memcpy(&f, &u, 4); return f;
}
__device__ __forceinline__ u16 f2b(float f) {
  u32 u; __builtin_memcpy(&u, &f, 4);
  u += 0x7fffu + ((u >> 16) & 1u);   // RNE
  return (u16)(u >> 16);
}
__device__ __forceinline__ u16 f2b_rtz(float f) {
  u32 u; __builtin_memcpy(&u, &f, 4);
  return (u16)(u >> 16);            // truncate; bias cancels in softmax norm
}

// ---- merged weight transpose+convert: 4 weights, one launch ---------------
#define SZ_QKV (DIMM * NQKV)
#define SZ_PRJ (DIMM * DIMM)
#define SZ_F1  (DIMM * DFF)
#define SZ_F2  (DFF * DIMM)
__global__ __launch_bounds__(256) void transpose_all_k(
    const float* __restrict__ w_qkv, const float* __restrict__ w_prj,
    const float* __restrict__ w_f1,  const float* __restrict__ w_f2,
    u16* __restrict__ o_qkv, u16* __restrict__ o_prj,
    u16* __restrict__ o_f1,  u16* __restrict__ o_f2) {
  int idx = blockIdx.x * 256 + threadIdx.x;
  const float* W; u16* O; int Kd, Nd, off;
  if (idx < SZ_QKV)                         { W = w_qkv; O = o_qkv; Kd = DIMM; Nd = NQKV; off = idx; }
  else if (idx < SZ_QKV + SZ_PRJ)           { W = w_prj; O = o_prj; Kd = DIMM; Nd = DIMM; off = idx - SZ_QKV; }
  else if (idx < SZ_QKV + SZ_PRJ + SZ_F1)   { W = w_f1;  O = o_f1;  Kd = DIMM; Nd = DFF;  off = idx - SZ_QKV - SZ_PRJ; }
  else                                      { W = w_f2;  O = o_f2;  Kd = DFF;  Nd = DIMM; off = idx - SZ_QKV - SZ_PRJ - SZ_F1; }
  int n = off / Kd, k = off - n * Kd;
  O[off] = f2b(W[(size_t)k * Nd + n]);
}

// ---------------- LayerNorm f32 -> bf16 (one wave per 512-row) -------------
__global__ __launch_bounds__(256) void ln_f32b_k(const float* __restrict__ X,
    const float* __restrict__ G, const float* __restrict__ Bb, u16* __restrict__ out) {
  int w = threadIdx.x >> 6, lane = threadIdx.x & 63;
  size_t row = (size_t)blockIdx.x * 4 + w;
  const float* xr = X + row * DIMM;
  float v[8];
  *(float4*)&v[0] = *(const float4*)(xr + lane * 8);
  *(float4*)&v[4] = *(const float4*)(xr + lane * 8 + 4);
  float s = 0.f, s2 = 0.f;
#pragma unroll
  for (int j = 0; j < 8; j++) { s += v[j]; s2 += v[j] * v[j]; }
#pragma unroll
  for (int m = 1; m < 64; m <<= 1) { s += __shfl_xor(s, m); s2 += __shfl_xor(s2, m); }
  float mu = s * (1.f / DIMM);
  float rsd = rsqrtf(s2 * (1.f / DIMM) - mu * mu + 1e-5f);
  float g[8], bb[8];
  *(float4*)&g[0]  = *(const float4*)(G + lane * 8);
  *(float4*)&g[4]  = *(const float4*)(G + lane * 8 + 4);
  *(float4*)&bb[0] = *(const float4*)(Bb + lane * 8);
  *(float4*)&bb[4] = *(const float4*)(Bb + lane * 8 + 4);
  uint4 ov; u16* os = (u16*)&ov;
#pragma unroll
  for (int j = 0; j < 8; j++) os[j] = f2b((v[j] - mu) * rsd * g[j] + bb[j]);
  *(uint4*)(out + row * DIMM + lane * 8) = ov;
}

// -------- MFMA GEMM: C[M,N] = A[M,K](bf16) @ BT[N,K](bf16)^T + bias --------
// 2-phase double-buffered pipeline (verified best: R5/R6 bench; the T4
// counted-vmcnt variant REGRESSED ~35us total -- reverted). STAGE(next)
// issued BEFORE COMPUTE(cur); single __syncthreads per k-step drains vmcnt
// AFTER the MFMA work.
// LDS tiles XOR-swizzled (T2) via pre-swizzled GLOBAL source (GLD16 dest must
// stay linear); read side applies the same involution.
// Macros (not lambdas): lambda+GLD16 tripped the toolchain (R2/R3 fails).
// TM x TN: TN=128 -> 2x2 wave grid (TM=128: WROWS 64; TM=64: WROWS 32,
// LDS 24KB -> 6 blocks/CU for latency-bound shapes). TN=64 -> 4x1 grid.
// EPI 0: f32   EPI 1: f32 (v + f32 resid)   EPI 2: gelu->bf16   EPI 3: bf16
template <int EPI, int TM, int TN, int BK>
__global__ __launch_bounds__(256) void gemm_bt(const u16* __restrict__ A,
    const u16* __restrict__ BT, const float* __restrict__ bias,
    void* __restrict__ Cout, const float* __restrict__ resid, int N, int Kd) {
  constexpr int CPR  = BK / 8;               // 16B chunks per row
  constexpr int CPRB = (BK == 64) ? 3 : 2;
  constexpr int RS   = (BK == 64) ? 0 : 1;   // swizzle: vary per 128B window
  constexpr int KK   = BK / 32;
  constexpr int WROWS = (TN == 128) ? TM / 2 : TM / 4;
  constexpr int MT   = WROWS / 16;
  __shared__ __align__(16) u16 a_s[2][TM * BK];
  __shared__ __align__(16) u16 b_s[2][TN * BK];
  int t = threadIdx.x, lane = t & 63, w = t >> 6;
  int l15 = lane & 15, quad = lane >> 4;
  int gx = gridDim.x;
  int lid = blockIdx.x + gx * blockIdx.y;
  int per = (gx * gridDim.y) >> 3;
  int nid = (lid & 7) * per + (lid >> 3);    // XCD-contiguous remap
  int bx = nid % gx, by = nid / gx;
  int m0 = by * TM, n0 = bx * TN;
  int wm = (TN == 128) ? (w >> 1) * WROWS : w * WROWS;
  int wn = (TN == 128) ? (w & 1) * 64 : 0;
  f32x4 z4 = {0.f, 0.f, 0.f, 0.f};
  f32x4 acc[MT][4];
#pragma unroll
  for (int i = 0; i < MT; i++)
#pragma unroll
    for (int j = 0; j < 4; j++) acc[i][j] = z4;

#define GSTAGE(buf, ts) do {                                                  \
    int k0_ = (ts) * BK;                                                      \
    _Pragma("unroll")                                                         \
    for (int i = 0; i < TM * CPR / 256; i++) {                                \
      int c_ = t + i * 256;                                                   \
      int row_ = c_ >> CPRB, pos_ = c_ & (CPR - 1);                           \
      int ch_ = (pos_ ^ (row_ >> RS)) & (CPR - 1);                            \
      GLD16(A + (size_t)(m0 + row_) * Kd + k0_ + ch_ * 8, &a_s[buf][c_ * 8]); \
    }                                                                         \
    _Pragma("unroll")                                                         \
    for (int i = 0; i < TN * CPR / 256; i++) {                                \
      int c_ = t + i * 256;                                                   \
      int row_ = c_ >> CPRB, pos_ = c_ & (CPR - 1);                           \
      int ch_ = (pos_ ^ (row_ >> RS)) & (CPR - 1);                            \
      GLD16(BT + (size_t)(n0 + row_) * Kd + k0_ + ch_ * 8, &b_s[buf][c_ * 8]);\
    }                                                                         \
  } while (0)

#define GCOMPUTE(buf) do {                                                    \
    bf16x8 af[MT][KK], bfm[4][KK];                                            \
    _Pragma("unroll")                                                         \
    for (int mt = 0; mt < MT; mt++) {                                         \
      _Pragma("unroll")                                                       \
      for (int kk = 0; kk < KK; kk++) {                                       \
        int row_ = wm + mt * 16 + l15;                                        \
        int pos_ = ((kk * 4 + quad) ^ (row_ >> RS)) & (CPR - 1);              \
        af[mt][kk] = *(const bf16x8*)&a_s[buf][row_ * BK + pos_ * 8];         \
      }                                                                       \
    }                                                                         \
    _Pragma("unroll")                                                         \
    for (int nt = 0; nt < 4; nt++) {                                          \
      _Pragma("unroll")                                                       \
      for (int kk = 0; kk < KK; kk++) {                                       \
        int row_ = wn + nt * 16 + l15;                                        \
        int pos_ = ((kk * 4 + quad) ^ (row_ >> RS)) & (CPR - 1);              \
        bfm[nt][kk] = *(const bf16x8*)&b_s[buf][row_ * BK + pos_ * 8];        \
      }                                                                       \
    }                                                                         \
    _Pragma("unroll")                                                         \
    for (int kk = 0; kk < KK; kk++)                                           \
      _Pragma("unroll")                                                       \
      for (int mt = 0; mt < MT; mt++)                                         \
        _Pragma("unroll")                                                     \
        for (int nt = 0; nt < 4; nt++)                                        \
          acc[mt][nt] = __builtin_amdgcn_mfma_f32_16x16x32_bf16(              \
              af[mt][kk], bfm[nt][kk], acc[mt][nt], 0, 0, 0);                 \
  } while (0)

  GSTAGE(0, 0);
  __syncthreads();                 // tile 0 ready (full latency exposed once)
  int nsteps = Kd / BK;            // always even (8/16/32)
  for (int ts = 0; ts < nsteps; ts += 2) {
    GSTAGE(1, ts + 1);             // issue next tile's loads first
    GCOMPUTE(0);
    __syncthreads();               // implicit vmcnt(0) AFTER compute
    if (ts + 2 < nsteps) GSTAGE(0, ts + 2);
    GCOMPUTE(1);
    __syncthreads();
  }
#undef GSTAGE
#undef GCOMPUTE

#pragma unroll
  for (int nt = 0; nt < 4; nt++) {
    int col = n0 + wn + nt * 16 + l15;
    float bv = bias[col];
#pragma unroll
    for (int mt = 0; mt < MT; mt++) {
#pragma unroll
      for (int r = 0; r < 4; r++) {
        int rw = m0 + wm + mt * 16 + quad * 4 + r;
        float v = acc[mt][nt][r] + bv;
        size_t off = (size_t)rw * N + col;
        if (EPI == 0) {
          ((float*)Cout)[off] = v;
        } else if (EPI == 1) {
          ((float*)Cout)[off] = v + resid[off];
        } else if (EPI == 2) {
          ((u16*)Cout)[off] = f2b(0.5f * v * (1.f + erff(v * 0.70710678118654752f)));
        } else {
          ((u16*)Cout)[off] = f2b(v);
        }
      }
    }
  }
}

// ------- RoPE + reorg qkv[BS][1536] bf16 -> Q,K,V [B*H][S][HD] bf16 --------
// Q pre-scaled by (1/sqrt(HD)) * log2(e) so attention can use exp2.
#define QSCALE 0.18033688f
__global__ __launch_bounds__(256) void rope_k(const u16* __restrict__ qkv,
    const float* __restrict__ C, const float* __restrict__ Sn,
    u16* __restrict__ Qo, u16* __restrict__ Ko, u16* __restrict__ Vo) {
  int idx = blockIdx.x * 256 + threadIdx.x;   // one 8-elem chunk
  int row = idx / 192;                        // (b*SEQ + s)
  int cn = idx - row * 192;
  int n0 = cn * 8;
  int comp = n0 >> 9;
  int hh = (n0 >> 6) & 7;
  int d0 = n0 & 63;
  int b = row >> 11, s = row & 2047;
  const u16* src = qkv + (size_t)row * NQKV;
  uint4 val = *(const uint4*)(src + n0);
  u16* vs = (u16*)&val;
  size_t oo = ((size_t)((b << 3) + hh) * SEQ + s) * HD + d0;
  if (comp == 2) { *(uint4*)(Vo + oo) = val; return; }
  uint4 pv = *(const uint4*)(src + (n0 ^ 32));        // rotate-half partner
  u16* ps = (u16*)&pv;
  float cv[8], sv[8];
  *(float4*)&cv[0] = *(const float4*)(C + s * HD + d0);
  *(float4*)&cv[4] = *(const float4*)(C + s * HD + d0 + 4);
  *(float4*)&sv[0] = *(const float4*)(Sn + s * HD + d0);
  *(float4*)&sv[4] = *(const float4*)(Sn + s * HD + d0 + 4);
  float sgn = (d0 & 32) ? 1.f : -1.f;
  float sc = (comp == 0) ? QSCALE : 1.f;
  uint4 ov; u16* os = (u16*)&ov;
#pragma unroll
  for (int j = 0; j < 8; j++)
    os[j] = f2b(sc * (b2f(vs[j]) * cv[j] + sgn * b2f(ps[j]) * sv[j]));
  *(uint4*)((comp == 0 ? Qo : Ko) + oo) = ov;
}

// ------------- V transpose: [bh][s][d] -> Vt [bh][d][s] (bf16) -------------
__global__ __launch_bounds__(256) void vtrans_k(const u16* __restrict__ V,
                                                u16* __restrict__ Vt) {
  __shared__ u16 ld[64 * 72];
  int t = threadIdx.x;
  int bh = blockIdx.x >> 5;          // 32 s-tiles per bh
  int s0 = (blockIdx.x & 31) * 64;
  const u16* src = V + (size_t)bh * SEQ * HD + (size_t)s0 * HD;
  u16* dst = Vt + (size_t)bh * SEQ * HD;
#pragma unroll
  for (int i = 0; i < 2; i++) {
    int c = t + i * 256, s = c >> 3, cp = c & 7;
    *(uint4*)&ld[s * 72 + ((cp ^ (s >> 3)) << 3)] =
        *(const uint4*)(src + (size_t)s * HD + cp * 8);
  }
  __syncthreads();
#pragma unroll
  for (int i = 0; i < 2; i++) {
    int c = t + i * 256, d = c >> 3, sc = c & 7;
    uint4 ov; u16* os = (u16*)&ov;
#pragma unroll
    for (int j = 0; j < 8; j++) {
      int s = sc * 8 + j;
      os[j] = ld[s * 72 + (((d >> 3) ^ (s >> 3)) << 3) + (d & 7)];
    }
    *(uint4*)(dst + (size_t)d * SEQ + s0 + sc * 8) = ov;
  }
}

// ---------------- flash attention, MFMA bf16, sum-softmax ------------------
// R5/R6-verified form (76.7us): 8 waves, 128-row q tile, V pre-transposed,
// P chunk-XOR-swizzled, direct bf16 output. K-split/combine REVERTED (zero
// attn gain, +6us combine cost). Known plateau: the per-tile serial chain
// (QK MFMA -> exp2/pack VALU -> P LDS round-trip -> PV MFMA) -- future
// round: swapped-QK in-register softmax (T12) to remove P_lds entirely.
__global__ __launch_bounds__(512) void attn_flash_k(const u16* __restrict__ Qg,
    const u16* __restrict__ Kg, const u16* __restrict__ Vtg, u16* __restrict__ Og) {
  __shared__ u16 q_s[128 * 72];    // Q tile, then P (rows = q rows)
  __shared__ u16 k_s[64 * 72];     // K rows (key-major)
  __shared__ u16 vt_s[64 * 72];    // V^T rows (d-major)
  int t = threadIdx.x, lane = t & 63, w = t >> 6;   // w in 0..7
  int l15 = lane & 15, quad = lane >> 4;
  int lid = blockIdx.x;                      // 512 blocks
  int nid = (lid & 7) * 64 + (lid >> 3);     // XCD-contiguous remap
  int bh = nid >> 4;                         // 16 q-tiles per (b,h)
  int qt0 = (nid & 15) * 128;
  int b = bh >> 3, h = bh & 7;
  const u16* Qp = Qg + (size_t)bh * SEQ * HD;
  const u16* Kp = Kg + (size_t)bh * SEQ * HD;
  const u16* Vp = Vtg + (size_t)bh * SEQ * HD;   // [d][s]
  int row = t >> 3, ch = t & 7;    // staging: K -> row=key, V^T -> row=d

  // P-swizzle constants (computed once):
  int sW = (w * 4 + quad) & 7;
  int pcol[4];
#pragma unroll
  for (int n = 0; n < 4; n++)
    pcol[n] = (((n * 2 + (l15 >> 3)) ^ sW) << 3) + (l15 & 7);
  int sR = (w * 4 + (l15 >> 2)) & 7;
  int pch[2];
#pragma unroll
  for (int kk = 0; kk < 2; kk++)
    pch[kk] = ((kk * 4 + quad) ^ sR) << 3;

  // stage Q tile (128 rows)
#pragma unroll
  for (int i = 0; i < 2; i++) {
    int c = t + i * 512, qr = c >> 3, qc = c & 7;
    *(uint4*)&q_s[qr * 72 + qc * 8] = *(const uint4*)(Qp + (size_t)(qt0 + qr) * HD + qc * 8);
  }
  // prefetch K/V tile 0 into registers
  uint4 kr = *(const uint4*)(Kp + (size_t)row * HD + ch * 8);
  uint4 vr = *(const uint4*)(Vp + (size_t)row * SEQ + ch * 8);
  __syncthreads();
  bf16x8 qa[2];
  qa[0] = *(const bf16x8*)&q_s[(w * 16 + l15) * 72 + quad * 8];
  qa[1] = *(const bf16x8*)&q_s[(w * 16 + l15) * 72 + 32 + quad * 8];
  u16* p_s = q_s;                  // q_s dead after qa load
  f32x4 z4 = {0.f, 0.f, 0.f, 0.f};
  f32x4 of[4];
#pragma unroll
  for (int n = 0; n < 4; n++) of[n] = z4;
  float lrun[4] = {};

  for (int kt = 0; kt < SEQ; kt += 64) {
    __syncthreads();               // prior tile's LDS reads drained
    *(uint4*)&k_s[row * 72 + ch * 8] = kr;
    *(uint4*)&vt_s[row * 72 + ch * 8] = vr;
    __syncthreads();               // staging visible
    if (kt + 64 < SEQ) {           // prefetch next tile
      kr = *(const uint4*)(Kp + (size_t)(kt + 64 + row) * HD + ch * 8);
      vr = *(const uint4*)(Vp + (size_t)row * SEQ + kt + 64 + ch * 8);
    }
    // S = Q K^T: sf[n] = S[q=w*16+quad*4+r][key=n*16+l15]
    f32x4 sf[4];
#pragma unroll
    for (int n = 0; n < 4; n++) sf[n] = z4;
    __builtin_amdgcn_s_setprio(1);
#pragma unroll
    for (int kk = 0; kk < 2; kk++)
#pragma unroll
      for (int n = 0; n < 4; n++) {
        bf16x8 kb = *(const bf16x8*)&k_s[(n * 16 + l15) * 72 + kk * 32 + quad * 8];
        sf[n] = __builtin_amdgcn_mfma_f32_16x16x32_bf16(qa[kk], kb, sf[n], 0, 0, 0);
      }
    __builtin_amdgcn_s_setprio(0);
    // p = exp2(s) (Q carried log2e/8); store RTZ bf16 swizzled; defer norm
#pragma unroll
    for (int r = 0; r < 4; r++) {
      int prow = (w * 16 + quad * 4 + r) * 72;
#pragma unroll
      for (int n = 0; n < 4; n++) {
        float pp = exp2f(sf[n][r]);
        lrun[r] += pp;
        p_s[prow + pcol[n]] = f2b_rtz(pp);
      }
    }
    // O += P V: vb rows are d (V^T), conflict-free row pattern
    __builtin_amdgcn_s_setprio(1);
#pragma unroll
    for (int kk = 0; kk < 2; kk++) {
      bf16x8 pa = *(const bf16x8*)&p_s[(w * 16 + l15) * 72 + pch[kk]];
#pragma unroll
      for (int n = 0; n < 4; n++) {
        bf16x8 vb = *(const bf16x8*)&vt_s[(n * 16 + l15) * 72 + kk * 32 + quad * 8];
        of[n] = __builtin_amdgcn_mfma_f32_16x16x32_bf16(pa, vb, of[n], 0, 0, 0);
      }
    }
    __builtin_amdgcn_s_setprio(0);
  }
#pragma unroll
  for (int r = 0; r < 4; r++) {
    float l = lrun[r];
#pragma unroll
    for (int m = 1; m < 16; m <<= 1) l += __shfl_xor(l, m);
    float inv = 1.f / l;
    size_t orow = (size_t)(b * SEQ + qt0 + w * 16 + quad * 4 + r);
#pragma unroll
    for (int n = 0; n < 4; n++)
      Og[orow * DIMM + h * HD + n * 16 + l15] = f2b(of[n][r] * inv);
  }
}

// ---------------------------------------------------------------------------
extern "C" void kernel_launch(void* const* d_in, const int* in_sizes, int n_in,
                              void* d_out, int out_size, void* d_ws, size_t ws_size,
                              hipStream_t stream) {
  const float* x    = (const float*)d_in[0];
  const float* rc   = (const float*)d_in[1];
  const float* rsn  = (const float*)d_in[2];
  const float* n1g  = (const float*)d_in[3];
  const float* n1b  = (const float*)d_in[4];
  const float* n2g  = (const float*)d_in[5];
  const float* n2b  = (const float*)d_in[6];
  const float* wqkv = (const float*)d_in[7];
  const float* bqkv = (const float*)d_in[8];
  const float* wprj = (const float*)d_in[9];
  const float* bprj = (const float*)d_in[10];
  const float* wf1  = (const float*)d_in[11];
  const float* bf1  = (const float*)d_in[12];
  const float* wf2  = (const float*)d_in[13];
  const float* bf2  = (const float*)d_in[14];

  char* p = (char*)d_ws;
  u16*   wqkvT = (u16*)p;                   // 1.5 MB
  u16*   wprjT = (u16*)(p + (2u  << 20));   // 0.5 MB
  u16*   wf1T  = (u16*)(p + (3u  << 20));   // 2 MB
  u16*   wf2T  = (u16*)(p + (5u  << 20));   // 2 MB
  u16*   h1    = (u16*)(p + (8u  << 20));   // 8 MB bf16: LN1 out / ob / h2
  u16*   qkvb  = (u16*)(p + (16u << 20));   // 24 MB bf16
  u16*   Vt    = (u16*)(p + (40u << 20));   // 8 MB bf16 (dead before FC1's mid)
  u16*   Qb    = (u16*)(p + (64u << 20));   // 8 MB bf16
  u16*   Kb    = (u16*)(p + (72u << 20));   // 8 MB bf16
  u16*   Vb    = (u16*)(p + (80u << 20));   // 8 MB bf16
  float* x2    = (float*)(p + (88u << 20)); // 16 MB f32 residual stream
  u16*   ob    = h1;                        // h1 dead after QKV gemm
  u16*   h2    = h1;                        // ob dead after proj gemm
  u16*   mid   = qkvb;                      // 32 MB bf16 region (qkvb+Vt dead)

  transpose_all_k<<<dim3((SZ_QKV + SZ_PRJ + SZ_F1 + SZ_F2) / 256), 256, 0, stream>>>(
      wqkv, wprj, wf1, wf2, wqkvT, wprjT, wf1T, wf2T);

  ln_f32b_k<<<dim3(BS / 4), 256, 0, stream>>>(x, n1g, n1b, h1);

  gemm_bt<3, 64, 128, 32><<<dim3(NQKV / 128, BS / 64), 256, 0, stream>>>(h1, wqkvT, bqkv, qkvb, nullptr, NQKV, DIMM);

  rope_k<<<dim3(BS * NQKV / 8 / 256), 256, 0, stream>>>(qkvb, rc, rsn, Qb, Kb, Vb);

  vtrans_k<<<dim3(32 * (SEQ / 64)), 256, 0, stream>>>(Vb, Vt);

  attn_flash_k<<<dim3(32 * (SEQ / 128)), 512, 0, stream>>>(Qb, Kb, Vt, ob);

  gemm_bt<1, 64, 64, 64><<<dim3(DIMM / 64, BS / 64), 256, 0, stream>>>(ob, wprjT, bprj, x2, x, DIMM, DIMM);

  ln_f32b_k<<<dim3(BS / 4), 256, 0, stream>>>(x2, n2g, n2b, h2);

  gemm_bt<2, 64, 128, 32><<<dim3(DFF / 128, BS / 64), 256, 0, stream>>>(h2, wf1T, bf1, mid, nullptr, DFF, DIMM);

  gemm_bt<1, 64, 64, 64><<<dim3(DIMM / 64, BS / 64), 256, 0, stream>>>(mid, wf2T, bf2, (float*)d_out, x2, DIMM, DFF);
}